// Round 1
// baseline (392.810 us; speedup 1.0000x reference)
//
#include <hip/hip_runtime.h>

#define NN 262144
#define DD 128
#define HH 132

typedef __attribute__((ext_vector_type(8))) short short8;
typedef __attribute__((ext_vector_type(4))) float f32x4;

__device__ __forceinline__ unsigned short f2b(float x){
  union { float f; unsigned int u; } c; c.f = x;
  unsigned int u = c.u;
  unsigned int r = (u + 0x7FFFu + ((u >> 16) & 1u)) >> 16;
  return (unsigned short)r;
}

// ---------------- precompute: Wfold = Wm@Wu, bias_r = K*bm@Wu + bu ----------------
__global__ void prep1(const float* __restrict__ Wm, const float* __restrict__ Wu,
                      const float* __restrict__ bm, const float* __restrict__ bu,
                      float* __restrict__ Wfold, float* __restrict__ bias_r)
{
  int j = threadIdx.x;          // 0..127
  int i = blockIdx.x;           // 0..128 (128 => bias row)
  if (i < 128){
    float s = 0.f;
    for (int k = 0; k < 128; ++k) s += Wm[i*128 + k] * Wu[k*128 + j];
    Wfold[i*128 + j] = s;
  } else {
    float s = bu[j];
    for (int m = 0; m < 128; ++m) s += 8.0f * bm[m] * Wu[m*128 + j];
    bias_r[j] = s;
  }
}

// ---------------- precompute: transposed, padded, bf16 weights + folded biases ----
// W1t [160][256] : rows(out c) 0..131 real; k 0..127 = W0top, k 128..255 = Wfold@W0bot
// W2t [160][160], W3t [160][160], W4t [128][160]
__global__ void prep2(const float* __restrict__ W0, const float* __restrict__ b0,
                      const float* __restrict__ W1, const float* __restrict__ b1,
                      const float* __restrict__ W2, const float* __restrict__ b2,
                      const float* __restrict__ W3, const float* __restrict__ b3,
                      const float* __restrict__ Wfold, const float* __restrict__ bias_r,
                      unsigned short* __restrict__ W1t, unsigned short* __restrict__ W2t,
                      unsigned short* __restrict__ W3t, unsigned short* __restrict__ W4t,
                      float* __restrict__ c0p, float* __restrict__ b1p,
                      float* __restrict__ b2p, float* __restrict__ b3p)
{
  int g = blockIdx.x * 256 + threadIdx.x;
  if (g < 40960){                       // W1t: c = g%160, k = g/160
    int c = g % 160, k = g / 160;
    float v = 0.f;
    if (c < 132){
      if (k < 128) v = W0[k*132 + c];
      else {
        int i = k - 128; float s = 0.f;
        for (int m = 0; m < 128; ++m) s += Wfold[i*128 + m] * W0[(128 + m)*132 + c];
        v = s;
      }
    }
    W1t[c*256 + k] = f2b(v);
  } else if (g < 66560){                // W2t
    int idx = g - 40960; int c = idx % 160, k = idx / 160;
    float v = (c < 132 && k < 132) ? W1[k*132 + c] : 0.f;
    W2t[c*160 + k] = f2b(v);
  } else if (g < 92160){                // W3t
    int idx = g - 66560; int c = idx % 160, k = idx / 160;
    float v = (c < 132 && k < 132) ? W2[k*132 + c] : 0.f;
    W3t[c*160 + k] = f2b(v);
  } else if (g < 112640){               // W4t [128][160]
    int idx = g - 92160; int c = idx & 127, k = idx >> 7;
    float v = (k < 132) ? W3[k*128 + c] : 0.f;
    W4t[c*160 + k] = f2b(v);
  } else if (g < 113248){               // biases
    int idx = g - 112640;
    if (idx < 160){
      int c = idx; float v = 0.f;
      if (c < 132){
        float s = b0[c];
        for (int k = 0; k < 128; ++k) s += bias_r[k] * W0[(128 + k)*132 + c];
        v = s;
      }
      c0p[c] = v;
    } else if (idx < 320){ int c = idx - 160; b1p[c] = (c < 132) ? b1[c] : 0.f; }
    else if (idx < 480){ int c = idx - 320; b2p[c] = (c < 132) ? b2[c] : 0.f; }
    else               { int c = idx - 480; b3p[c] = b3[c]; }
  }
}

// ---------------- main fused kernel ----------------
// LDS (ushort units): act [64][256] @ 0 (stride 512B), h1 [64][192] @ 16384 (stride 384B)
// h2 reuses act region, h3 reuses h1 region.  XOR swizzle: byte ^= (row&7)<<4.
__device__ __forceinline__ int swzidx(int row, int colByte, int strideB){
  return (row*strideB + (colByte ^ ((row & 7) << 4))) >> 1;
}

template<int KD, int AST, int NT, bool RELU>
__device__ __forceinline__ void gemm_block(const unsigned short* __restrict__ smem,
                                           int abase, int hbase,
                                           const unsigned short* __restrict__ Bt,
                                           const float* __restrict__ bias,
                                           unsigned short* __restrict__ smw)
{
  const int l  = threadIdx.x & 63;
  const int w  = threadIdx.x >> 6;
  const int lr = l & 15, lg = l >> 4;
  constexpr int MS = (NT + 3) / 4;
  f32x4 acc[4][MS];
  #pragma unroll
  for (int a = 0; a < 4; ++a)
    #pragma unroll
    for (int s = 0; s < MS; ++s) acc[a][s] = (f32x4){0.f,0.f,0.f,0.f};

  #pragma unroll
  for (int ks = 0; ks < KD/32; ++ks){
    short8 af[4];
    #pragma unroll
    for (int rt = 0; rt < 4; ++rt){
      int row = rt*16 + lr;
      int cb  = (ks*32 + lg*8) * 2;
      af[rt] = *(const short8*)&smem[abase + swzidx(row, cb, AST)];
    }
    short8 bf[MS];
    #pragma unroll
    for (int s = 0; s < MS; ++s){
      int ct = w + 4*s;
      if (ct < NT) bf[s] = *(const short8*)&Bt[(ct*16 + lr)*KD + ks*32 + lg*8];
    }
    #pragma unroll
    for (int rt = 0; rt < 4; ++rt)
      #pragma unroll
      for (int s = 0; s < MS; ++s){
        int ct = w + 4*s;
        if (ct < NT)
          acc[rt][s] = __builtin_amdgcn_mfma_f32_16x16x32_bf16(af[rt], bf[s], acc[rt][s], 0, 0, 0);
      }
  }
  #pragma unroll
  for (int s = 0; s < MS; ++s){
    int ct = w + 4*s;
    if (ct >= NT) continue;
    float bv = bias[ct*16 + lr];
    #pragma unroll
    for (int rt = 0; rt < 4; ++rt){
      #pragma unroll
      for (int r = 0; r < 4; ++r){
        float v = acc[rt][s][r] + bv;
        if (RELU) v = fmaxf(v, 0.f);
        int row = rt*16 + lg*4 + r;
        int cb  = (ct*16 + lr) * 2;
        smw[hbase + swzidx(row, cb, 384)] = f2b(v);
      }
    }
  }
}

template<int KD, int AST>
__device__ __forceinline__ void gemm_out(const unsigned short* __restrict__ smem,
                                         int abase,
                                         const unsigned short* __restrict__ Bt,
                                         const float* __restrict__ bias,
                                         float* __restrict__ out, long n0)
{
  const int l  = threadIdx.x & 63;
  const int w  = threadIdx.x >> 6;
  const int lr = l & 15, lg = l >> 4;
  f32x4 acc[4][2];
  #pragma unroll
  for (int a = 0; a < 4; ++a){ acc[a][0] = (f32x4){0.f,0.f,0.f,0.f}; acc[a][1] = (f32x4){0.f,0.f,0.f,0.f}; }

  #pragma unroll
  for (int ks = 0; ks < KD/32; ++ks){
    short8 af[4];
    #pragma unroll
    for (int rt = 0; rt < 4; ++rt){
      int row = rt*16 + lr;
      int cb  = (ks*32 + lg*8) * 2;
      af[rt] = *(const short8*)&smem[abase + swzidx(row, cb, AST)];
    }
    short8 bf[2];
    #pragma unroll
    for (int s = 0; s < 2; ++s){
      int ct = w + 4*s;
      bf[s] = *(const short8*)&Bt[(ct*16 + lr)*KD + ks*32 + lg*8];
    }
    #pragma unroll
    for (int rt = 0; rt < 4; ++rt)
      #pragma unroll
      for (int s = 0; s < 2; ++s)
        acc[rt][s] = __builtin_amdgcn_mfma_f32_16x16x32_bf16(af[rt], bf[s], acc[rt][s], 0, 0, 0);
  }
  #pragma unroll
  for (int s = 0; s < 2; ++s){
    int ct = w + 4*s;
    float bv = bias[ct*16 + lr];
    #pragma unroll
    for (int rt = 0; rt < 4; ++rt){
      #pragma unroll
      for (int r = 0; r < 4; ++r){
        int row = rt*16 + lg*4 + r;
        out[(n0 + row)*128 + ct*16 + lr] = acc[rt][s][r] + bv;
      }
    }
  }
}

__global__ __launch_bounds__(256, 2) void fused_main(
    const float* __restrict__ sig, const float* __restrict__ comp,
    const unsigned short* __restrict__ W1t, const unsigned short* __restrict__ W2t,
    const unsigned short* __restrict__ W3t, const unsigned short* __restrict__ W4t,
    const float* __restrict__ c0p, const float* __restrict__ b1p,
    const float* __restrict__ b2p, const float* __restrict__ b3p,
    float* __restrict__ out)
{
  __shared__ unsigned short smem[28672];   // 56 KiB
  const int ACT = 0;        // [64] rows, 512 B stride (256 bf16: signal | summed)
  const int H1  = 16384;    // [64] rows, 384 B stride
  const int H2  = 0;        // reuse act
  const int H3  = 16384;    // reuse h1

  const int t = threadIdx.x;
  const long n0 = (long)blockIdx.x * 64;

  // ---- Phase A: stream components (sum over K=8) + signal, write bf16 act tile ----
  const float4* __restrict__ compv = (const float4*)comp;
  const float4* __restrict__ sigv  = (const float4*)sig;
  float4 sum[8], sg[8];
  int rowj[8], c4j[8];
  #pragma unroll
  for (int j = 0; j < 8; ++j){
    int f = t + 256*j;
    rowj[j] = f >> 5; c4j[j] = f & 31;
    long base = (n0 + rowj[j])*32 + c4j[j];
    sg[j]  = sigv[base];
    sum[j] = compv[base];
  }
  #pragma unroll
  for (int k = 1; k < 8; ++k){
    #pragma unroll
    for (int j = 0; j < 8; ++j){
      long base = (long)k*(NN*32) + (n0 + rowj[j])*32 + c4j[j];
      float4 v = compv[base];
      sum[j].x += v.x; sum[j].y += v.y; sum[j].z += v.z; sum[j].w += v.w;
    }
  }
  #pragma unroll
  for (int j = 0; j < 8; ++j){
    int row = rowj[j];
    int cb  = c4j[j]*8;                  // byte offset of 4 bf16
    int mask = (row & 7) << 4;
    ushort4 ps, pm;
    ps.x=f2b(sg[j].x);  ps.y=f2b(sg[j].y);  ps.z=f2b(sg[j].z);  ps.w=f2b(sg[j].w);
    pm.x=f2b(sum[j].x); pm.y=f2b(sum[j].y); pm.z=f2b(sum[j].z); pm.w=f2b(sum[j].w);
    *(ushort4*)&smem[ACT + ((row*512 + (cb ^ mask)) >> 1)]         = ps;   // signal: cols 0..127
    *(ushort4*)&smem[ACT + ((row*512 + ((256 + cb) ^ mask)) >> 1)] = pm;   // summed: cols 128..255
  }
  __syncthreads();

  // ---- Phase B: MFMA GEMM chain ----
  gemm_block<256, 512, 10, true>(smem, ACT, H1, W1t, c0p, smem);
  __syncthreads();
  gemm_block<160, 384, 10, true>(smem, H1, H2, W2t, b1p, smem);
  __syncthreads();
  gemm_block<160, 384, 10, true>(smem, H2, H3, W3t, b2p, smem);
  __syncthreads();
  gemm_out<160, 384>(smem, H3, W4t, b3p, out, n0);
}

// ---------------- launch ----------------
extern "C" void kernel_launch(void* const* d_in, const int* in_sizes, int n_in,
                              void* d_out, int out_size, void* d_ws, size_t ws_size,
                              hipStream_t stream)
{
  const float* sig  = (const float*)d_in[0];
  const float* comp = (const float*)d_in[1];
  const float* Wm   = (const float*)d_in[2];
  const float* bm   = (const float*)d_in[3];
  const float* Wu   = (const float*)d_in[4];
  const float* bu   = (const float*)d_in[5];
  const float* W0   = (const float*)d_in[6];
  const float* b0   = (const float*)d_in[7];
  const float* W1   = (const float*)d_in[8];
  const float* b1   = (const float*)d_in[9];
  const float* W2   = (const float*)d_in[10];
  const float* b2   = (const float*)d_in[11];
  const float* W3   = (const float*)d_in[12];
  const float* b3   = (const float*)d_in[13];

  char* ws = (char*)d_ws;
  float* Wfold  = (float*)(ws + 0);          // 65536
  float* bias_r = (float*)(ws + 65536);      // 512
  float* c0p    = (float*)(ws + 66048);      // 640
  float* b1p    = (float*)(ws + 66688);      // 640
  float* b2p    = (float*)(ws + 67328);      // 640
  float* b3p    = (float*)(ws + 67968);      // 512
  unsigned short* W1t = (unsigned short*)(ws + 69632);    // 160*256*2 = 81920
  unsigned short* W2t = (unsigned short*)(ws + 151552);   // 160*160*2 = 51200
  unsigned short* W3t = (unsigned short*)(ws + 202752);   // 51200
  unsigned short* W4t = (unsigned short*)(ws + 253952);   // 128*160*2 = 40960

  prep1<<<129, 128, 0, stream>>>(Wm, Wu, bm, bu, Wfold, bias_r);
  prep2<<<443, 256, 0, stream>>>(W0, b0, W1, b1, W2, b2, W3, b3, Wfold, bias_r,
                                 W1t, W2t, W3t, W4t, c0p, b1p, b2p, b3p);
  fused_main<<<4096, 256, 0, stream>>>(sig, comp, W1t, W2t, W3t, W4t,
                                       c0p, b1p, b2p, b3p, (float*)d_out);
}

// Round 2
// 383.104 us; speedup vs baseline: 1.0253x; 1.0253x over previous
//
#include <hip/hip_runtime.h>

#define NN 262144
#define DD 128
#define HH 132

typedef __attribute__((ext_vector_type(8))) short short8;
typedef __attribute__((ext_vector_type(4))) float f32x4;

__device__ __forceinline__ unsigned short f2b(float x){
  union { float f; unsigned int u; } c; c.f = x;
  unsigned int u = c.u;
  unsigned int r = (u + 0x7FFFu + ((u >> 16) & 1u)) >> 16;
  return (unsigned short)r;
}

// ---------------- precompute: Wfold = Wm@Wu, bias_r = K*bm@Wu + bu ----------------
__global__ void prep1(const float* __restrict__ Wm, const float* __restrict__ Wu,
                      const float* __restrict__ bm, const float* __restrict__ bu,
                      float* __restrict__ Wfold, float* __restrict__ bias_r)
{
  int j = threadIdx.x;          // 0..127
  int i = blockIdx.x;           // 0..128 (128 => bias row)
  if (i < 128){
    float s = 0.f;
    for (int k = 0; k < 128; ++k) s += Wm[i*128 + k] * Wu[k*128 + j];
    Wfold[i*128 + j] = s;
  } else {
    float s = bu[j];
    for (int m = 0; m < 128; ++m) s += 8.0f * bm[m] * Wu[m*128 + j];
    bias_r[j] = s;
  }
}

// ---------------- precompute: transposed, padded, bf16 weights + folded biases ----
// W1t [160][256] : rows(out c) 0..131 real; k 0..127 = W0top, k 128..255 = Wfold@W0bot
// W2t [160][160], W3t [160][160], W4t [128][160]
__global__ void prep2(const float* __restrict__ W0, const float* __restrict__ b0,
                      const float* __restrict__ W1, const float* __restrict__ b1,
                      const float* __restrict__ W2, const float* __restrict__ b2,
                      const float* __restrict__ W3, const float* __restrict__ b3,
                      const float* __restrict__ Wfold, const float* __restrict__ bias_r,
                      unsigned short* __restrict__ W1t, unsigned short* __restrict__ W2t,
                      unsigned short* __restrict__ W3t, unsigned short* __restrict__ W4t,
                      float* __restrict__ c0p, float* __restrict__ b1p,
                      float* __restrict__ b2p, float* __restrict__ b3p)
{
  int g = blockIdx.x * 256 + threadIdx.x;
  if (g < 40960){                       // W1t: c = g%160, k = g/160
    int c = g % 160, k = g / 160;
    float v = 0.f;
    if (c < 132){
      if (k < 128) v = W0[k*132 + c];
      else {
        int i = k - 128; float s = 0.f;
        for (int m = 0; m < 128; ++m) s += Wfold[i*128 + m] * W0[(128 + m)*132 + c];
        v = s;
      }
    }
    W1t[c*256 + k] = f2b(v);
  } else if (g < 66560){                // W2t
    int idx = g - 40960; int c = idx % 160, k = idx / 160;
    float v = (c < 132 && k < 132) ? W1[k*132 + c] : 0.f;
    W2t[c*160 + k] = f2b(v);
  } else if (g < 92160){                // W3t
    int idx = g - 66560; int c = idx % 160, k = idx / 160;
    float v = (c < 132 && k < 132) ? W2[k*132 + c] : 0.f;
    W3t[c*160 + k] = f2b(v);
  } else if (g < 112640){               // W4t [128][160]
    int idx = g - 92160; int c = idx & 127, k = idx >> 7;
    float v = (k < 132) ? W3[k*128 + c] : 0.f;
    W4t[c*160 + k] = f2b(v);
  } else if (g < 113248){               // biases
    int idx = g - 112640;
    if (idx < 160){
      int c = idx; float v = 0.f;
      if (c < 132){
        float s = b0[c];
        for (int k = 0; k < 128; ++k) s += bias_r[k] * W0[(128 + k)*132 + c];
        v = s;
      }
      c0p[c] = v;
    } else if (idx < 320){ int c = idx - 160; b1p[c] = (c < 132) ? b1[c] : 0.f; }
    else if (idx < 480){ int c = idx - 320; b2p[c] = (c < 132) ? b2[c] : 0.f; }
    else               { int c = idx - 480; b3p[c] = b3[c]; }
  }
}

// ---------------- main fused kernel ----------------
// LDS (ushort units):
//   ACT @ 0     : [64 nodes][256 bf16], row stride 512 B, XOR swizzle byte ^= (row&7)<<4
//   H   @ 16384 : [64 nodes][168 bf16], row stride 336 B (84 dw -> uniform bank spread)
// L1: read ACT -> write H ; L2: read H -> write ACT region ; L3: read ACT -> write H ;
// L4: read H -> global out.  Total LDS = 32 KiB + 21 KiB = 53 KiB -> 3 blocks/CU.
//
// Swapped-operand MFMA: D[feat][node] = W[feat][k] * act[node][k].
// Lane layout: col(lane&15)=node, row=(lane>>4)*4+r = feat -> each lane holds 4
// consecutive feats of one node -> vector ushort4/float4 epilogue writes.

template<int KD, bool SWZ, int FTW, bool RELU>
__device__ __forceinline__ void layer_lds(const unsigned short* __restrict__ smem, int rbase,
                                          const unsigned short* __restrict__ Wt,
                                          const float* __restrict__ bias,
                                          unsigned short* __restrict__ smw, int wbase)
{
  const int t  = threadIdx.x;
  const int w  = t >> 6;
  const int lr = t & 15, lg = (t & 63) >> 4;
  const int ntA = (w & 1) * 16;          // node rows [ntA, ntA+16) and [ntA+32, ...)
  const int f0  = (w >> 1) * FTW;        // feature tile start

  f32x4 acc[2][FTW];
  #pragma unroll
  for (int n2 = 0; n2 < 2; ++n2)
    #pragma unroll
    for (int fi = 0; fi < FTW; ++fi) acc[n2][fi] = (f32x4){0.f,0.f,0.f,0.f};

  #pragma unroll
  for (int ks = 0; ks < KD/32; ++ks){
    const int colu = ks*32 + lg*8;       // ushort col
    short8 bA, bB;
    if (SWZ){
      int cb = colu*2;
      int rA = ntA + lr, rB = ntA + 32 + lr;
      bA = *(const short8*)&smem[rbase + ((rA*512 + (cb ^ ((rA & 7) << 4))) >> 1)];
      bB = *(const short8*)&smem[rbase + ((rB*512 + (cb ^ ((rB & 7) << 4))) >> 1)];
    } else {
      bA = *(const short8*)&smem[rbase + (ntA + lr)*168 + colu];
      bB = *(const short8*)&smem[rbase + (ntA + 32 + lr)*168 + colu];
    }
    #pragma unroll
    for (int fi = 0; fi < FTW; ++fi){
      short8 aw = *(const short8*)&Wt[((f0 + fi)*16 + lr)*KD + colu];
      acc[0][fi] = __builtin_amdgcn_mfma_f32_16x16x32_bf16(aw, bA, acc[0][fi], 0, 0, 0);
      acc[1][fi] = __builtin_amdgcn_mfma_f32_16x16x32_bf16(aw, bB, acc[1][fi], 0, 0, 0);
    }
  }

  #pragma unroll
  for (int fi = 0; fi < FTW; ++fi){
    float4 bv = *(const float4*)&bias[(f0 + fi)*16 + lg*4];
    #pragma unroll
    for (int n2 = 0; n2 < 2; ++n2){
      int row = ntA + n2*32 + lr;
      float v0 = acc[n2][fi][0] + bv.x;
      float v1 = acc[n2][fi][1] + bv.y;
      float v2 = acc[n2][fi][2] + bv.z;
      float v3 = acc[n2][fi][3] + bv.w;
      if (RELU){ v0=fmaxf(v0,0.f); v1=fmaxf(v1,0.f); v2=fmaxf(v2,0.f); v3=fmaxf(v3,0.f); }
      ushort4 p; p.x=f2b(v0); p.y=f2b(v1); p.z=f2b(v2); p.w=f2b(v3);
      *(ushort4*)&smw[wbase + row*168 + (f0 + fi)*16 + lg*4] = p;
    }
  }
}

template<int KD, int FTW>
__device__ __forceinline__ void layer_out(const unsigned short* __restrict__ smem, int rbase,
                                          const unsigned short* __restrict__ Wt,
                                          const float* __restrict__ bias,
                                          float* __restrict__ out, long n0)
{
  const int t  = threadIdx.x;
  const int w  = t >> 6;
  const int lr = t & 15, lg = (t & 63) >> 4;
  const int ntA = (w & 1) * 16;
  const int f0  = (w >> 1) * FTW;

  f32x4 acc[2][FTW];
  #pragma unroll
  for (int n2 = 0; n2 < 2; ++n2)
    #pragma unroll
    for (int fi = 0; fi < FTW; ++fi) acc[n2][fi] = (f32x4){0.f,0.f,0.f,0.f};

  #pragma unroll
  for (int ks = 0; ks < KD/32; ++ks){
    const int colu = ks*32 + lg*8;
    short8 bA = *(const short8*)&smem[rbase + (ntA + lr)*168 + colu];
    short8 bB = *(const short8*)&smem[rbase + (ntA + 32 + lr)*168 + colu];
    #pragma unroll
    for (int fi = 0; fi < FTW; ++fi){
      short8 aw = *(const short8*)&Wt[((f0 + fi)*16 + lr)*KD + colu];
      acc[0][fi] = __builtin_amdgcn_mfma_f32_16x16x32_bf16(aw, bA, acc[0][fi], 0, 0, 0);
      acc[1][fi] = __builtin_amdgcn_mfma_f32_16x16x32_bf16(aw, bB, acc[1][fi], 0, 0, 0);
    }
  }

  #pragma unroll
  for (int fi = 0; fi < FTW; ++fi){
    float4 bv = *(const float4*)&bias[(f0 + fi)*16 + lg*4];
    #pragma unroll
    for (int n2 = 0; n2 < 2; ++n2){
      int row = ntA + n2*32 + lr;
      float4 o;
      o.x = acc[n2][fi][0] + bv.x;
      o.y = acc[n2][fi][1] + bv.y;
      o.z = acc[n2][fi][2] + bv.z;
      o.w = acc[n2][fi][3] + bv.w;
      *(float4*)&out[(n0 + row)*128 + (f0 + fi)*16 + lg*4] = o;
    }
  }
}

__global__ __launch_bounds__(256, 3) void fused_main(
    const float* __restrict__ sig, const float* __restrict__ comp,
    const unsigned short* __restrict__ W1t, const unsigned short* __restrict__ W2t,
    const unsigned short* __restrict__ W3t, const unsigned short* __restrict__ W4t,
    const float* __restrict__ c0p, const float* __restrict__ b1p,
    const float* __restrict__ b2p, const float* __restrict__ b3p,
    float* __restrict__ out)
{
  __shared__ unsigned short smem[27136];   // 53 KiB
  const int ACT = 0;
  const int H1  = 16384;

  const int t = threadIdx.x;
  const long n0 = (long)blockIdx.x * 64;

  // ---- Phase A: signal -> LDS immediately; sum components; write summed ----
  const float4* __restrict__ compv = (const float4*)comp;
  const float4* __restrict__ sigv  = (const float4*)sig;

  #pragma unroll
  for (int j = 0; j < 8; ++j){
    int f = t + 256*j;
    int row = f >> 5, c4 = f & 31;
    float4 v = sigv[n0*32 + f];
    int cb = c4*8, mask = (row & 7) << 4;
    ushort4 p; p.x=f2b(v.x); p.y=f2b(v.y); p.z=f2b(v.z); p.w=f2b(v.w);
    *(ushort4*)&smem[ACT + ((row*512 + (cb ^ mask)) >> 1)] = p;
  }

  float4 sum[8];
  #pragma unroll
  for (int j = 0; j < 8; ++j) sum[j] = compv[n0*32 + t + 256*j];
  #pragma unroll
  for (int k = 1; k < 8; ++k){
    #pragma unroll
    for (int j = 0; j < 8; ++j){
      float4 v = compv[(long)k*(NN*32) + n0*32 + t + 256*j];
      sum[j].x += v.x; sum[j].y += v.y; sum[j].z += v.z; sum[j].w += v.w;
    }
  }
  #pragma unroll
  for (int j = 0; j < 8; ++j){
    int f = t + 256*j;
    int row = f >> 5, c4 = f & 31;
    int cb = c4*8, mask = (row & 7) << 4;
    ushort4 p; p.x=f2b(sum[j].x); p.y=f2b(sum[j].y); p.z=f2b(sum[j].z); p.w=f2b(sum[j].w);
    *(ushort4*)&smem[ACT + ((row*512 + ((256 + cb) ^ mask)) >> 1)] = p;
  }
  __syncthreads();

  // ---- Phase B: 4-layer MFMA chain ----
  layer_lds<256, true,  5, true>(smem, ACT, W1t, c0p, smem, H1);
  __syncthreads();
  layer_lds<160, false, 5, true>(smem, H1,  W2t, b1p, smem, ACT);
  __syncthreads();
  layer_lds<160, false, 5, true>(smem, ACT, W3t, b2p, smem, H1);
  __syncthreads();
  layer_out<160, 4>(smem, H1, W4t, b3p, out, n0);
}

// ---------------- launch ----------------
extern "C" void kernel_launch(void* const* d_in, const int* in_sizes, int n_in,
                              void* d_out, int out_size, void* d_ws, size_t ws_size,
                              hipStream_t stream)
{
  const float* sig  = (const float*)d_in[0];
  const float* comp = (const float*)d_in[1];
  const float* Wm   = (const float*)d_in[2];
  const float* bm   = (const float*)d_in[3];
  const float* Wu   = (const float*)d_in[4];
  const float* bu   = (const float*)d_in[5];
  const float* W0   = (const float*)d_in[6];
  const float* b0   = (const float*)d_in[7];
  const float* W1   = (const float*)d_in[8];
  const float* b1   = (const float*)d_in[9];
  const float* W2   = (const float*)d_in[10];
  const float* b2   = (const float*)d_in[11];
  const float* W3   = (const float*)d_in[12];
  const float* b3   = (const float*)d_in[13];

  char* ws = (char*)d_ws;
  float* Wfold  = (float*)(ws + 0);          // 65536
  float* bias_r = (float*)(ws + 65536);      // 512
  float* c0p    = (float*)(ws + 66048);      // 640
  float* b1p    = (float*)(ws + 66688);      // 640
  float* b2p    = (float*)(ws + 67328);      // 640
  float* b3p    = (float*)(ws + 67968);      // 512
  unsigned short* W1t = (unsigned short*)(ws + 69632);    // 160*256*2 = 81920
  unsigned short* W2t = (unsigned short*)(ws + 151552);   // 160*160*2 = 51200
  unsigned short* W3t = (unsigned short*)(ws + 202752);   // 51200
  unsigned short* W4t = (unsigned short*)(ws + 253952);   // 128*160*2 = 40960

  prep1<<<129, 128, 0, stream>>>(Wm, Wu, bm, bu, Wfold, bias_r);
  prep2<<<443, 256, 0, stream>>>(W0, b0, W1, b1, W2, b2, W3, b3, Wfold, bias_r,
                                 W1t, W2t, W3t, W4t, c0p, b1p, b2p, b3p);
  fused_main<<<4096, 256, 0, stream>>>(sig, comp, W1t, W2t, W3t, W4t,
                                       c0p, b1p, b2p, b3p, (float*)d_out);
}